// Round 1
// baseline (470.161 us; speedup 1.0000x reference)
//
#include <hip/hip_runtime.h>

// Problem constants (B=8, Q=512, D=4096, H=1024)
#define BATCH 8
#define QLEN 512
#define DLEN 4096
#define HDIM 1024

// ---------- helpers ----------
typedef __attribute__((ext_vector_type(8))) short bf16x8;   // 8 bf16 in 4 VGPRs
typedef __attribute__((ext_vector_type(4))) float f32x4;
typedef __attribute__((ext_vector_type(4))) short s16x4;

__device__ __forceinline__ short f2bf(float f) {
    union { float f; unsigned u; } x; x.f = f;
    unsigned r = x.u + 0x7fffu + ((x.u >> 16) & 1u);   // RNE
    return (short)(r >> 16);
}

__device__ __forceinline__ void gload_lds16(const void* g, void* l) {
    __builtin_amdgcn_global_load_lds(
        (const __attribute__((address_space(1))) unsigned int*)g,
        (__attribute__((address_space(3))) unsigned int*)l,
        16, 0, 0);
}

// ---------- prep kernels ----------
// fp32 -> bf16 elementwise (vectorized float4 -> short4)
__global__ void cvt_f32_bf16(const float* __restrict__ in, short* __restrict__ out, int n4) {
    int i = blockIdx.x * blockDim.x + threadIdx.x;
    int stride = gridDim.x * blockDim.x;
    for (; i < n4; i += stride) {
        float4 x = ((const float4*)in)[i];
        s16x4 o = { f2bf(x.x), f2bf(x.y), f2bf(x.z), f2bf(x.w) };
        ((s16x4*)out)[i] = o;
    }
}

// proj_w [h][k] f32 -> Wt [k][h] bf16  (1024x1024), 32x32 LDS tile transpose
__global__ void transpose_w(const float* __restrict__ W, short* __restrict__ Wt) {
    __shared__ float t[32][33];
    const int hb = blockIdx.y * 32, kb = blockIdx.x * 32;
    #pragma unroll
    for (int i = 0; i < 4; ++i) {
        int h = threadIdx.y + i * 8;
        t[h][threadIdx.x] = W[(size_t)(hb + h) * HDIM + kb + threadIdx.x];
    }
    __syncthreads();
    #pragma unroll
    for (int i = 0; i < 4; ++i) {
        int k = threadIdx.y + i * 8;
        Wt[(size_t)(kb + k) * HDIM + hb + threadIdx.x] = f2bf(t[threadIdx.x][k]);
    }
}

// docs [b][d][h] f32 -> docsB [b][d][h] bf16  AND  docsT [b][h][d] bf16
__global__ void prep_docs(const float* __restrict__ docs,
                          short* __restrict__ docsB, short* __restrict__ docsT) {
    __shared__ float t[32][33];
    const int b = blockIdx.z;
    const int h0 = blockIdx.x * 32, d0 = blockIdx.y * 32;
    const float* src = docs + ((size_t)b * DLEN + d0) * HDIM + h0;
    #pragma unroll
    for (int i = 0; i < 4; ++i) {
        int d = threadIdx.y + i * 8;
        float v = src[(size_t)d * HDIM + threadIdx.x];
        t[d][threadIdx.x] = v;
        docsB[((size_t)b * DLEN + d0 + d) * HDIM + h0 + threadIdx.x] = f2bf(v);
    }
    __syncthreads();
    #pragma unroll
    for (int i = 0; i < 4; ++i) {
        int h = threadIdx.y + i * 8;
        docsT[((size_t)b * HDIM + h0 + h) * DLEN + d0 + threadIdx.x] = f2bf(t[threadIdx.x][h]);
    }
}

// ---------- GEMM: D[i][j] = dot(A_i, B_j), A:[M][K], B:[N][K], both bf16 row-major in K
// m97 structure: 128x128 tile, BK=32, 256 threads (2x2 waves of 64x64), global_load_lds w=16.
// EPI 0: bf16 out + bias   EPI 1: f32 out * scale   EPI 2: f32 out
#define BM 128
#define BN 128
#define BK 32

template<int EPI>
__global__ void gemm_bt(const short* __restrict__ A, const short* __restrict__ B,
                        void* __restrict__ Cv, const float* __restrict__ bias,
                        float scale, int M, int N, int K,
                        long long aB, long long bB, long long cB) {
    __shared__ short As[BM * BK];
    __shared__ short Bs[BN * BK];
    const int tid  = threadIdx.x;
    const int lane = tid & 63;
    const int wv   = tid >> 6;
    const int wr   = wv >> 1, wc = wv & 1;
    const size_t rowBase = (size_t)blockIdx.y * BM;
    const size_t colBase = (size_t)blockIdx.x * BN;
    const short* Ab = A + (size_t)blockIdx.z * aB;
    const short* Bb = B + (size_t)blockIdx.z * bB;

    f32x4 acc[4][4];
    #pragma unroll
    for (int m = 0; m < 4; ++m)
        #pragma unroll
        for (int n = 0; n < 4; ++n)
            acc[m][n] = (f32x4){0.f, 0.f, 0.f, 0.f};

    // staging chunks: chunk c covers LDS shorts [c*8, c*8+8) = row c>>2, k (c&3)*8
    const int c0 = tid, c1 = 256 + tid;
    const int r0 = c0 >> 2, k0 = (c0 & 3) << 3;
    const int r1 = c1 >> 2, k1 = (c1 & 3) << 3;
    const int lr = lane & 15;
    const int lk = (lane >> 4) << 3;

    for (int kt = 0; kt < K; kt += BK) {
        gload_lds16(Ab + (rowBase + r0) * K + kt + k0, As + c0 * 8);
        gload_lds16(Ab + (rowBase + r1) * K + kt + k1, As + c1 * 8);
        gload_lds16(Bb + (colBase + r0) * K + kt + k0, Bs + c0 * 8);
        gload_lds16(Bb + (colBase + r1) * K + kt + k1, Bs + c1 * 8);
        __syncthreads();

        bf16x8 af[4], bfr[4];
        #pragma unroll
        for (int m = 0; m < 4; ++m)
            af[m] = *(const bf16x8*)(As + (wr * 64 + m * 16 + lr) * BK + lk);
        #pragma unroll
        for (int n = 0; n < 4; ++n)
            bfr[n] = *(const bf16x8*)(Bs + (wc * 64 + n * 16 + lr) * BK + lk);

        #pragma unroll
        for (int m = 0; m < 4; ++m)
            #pragma unroll
            for (int n = 0; n < 4; ++n)
                acc[m][n] = __builtin_amdgcn_mfma_f32_16x16x32_bf16(af[m], bfr[n], acc[m][n], 0, 0, 0);
        __syncthreads();
    }

    // epilogue: C/D layout col=lane&15, row=(lane>>4)*4+reg  [m89/m91-verified]
    const int orow = (lane >> 4) << 2;
    const int ocol = lane & 15;
    #pragma unroll
    for (int n = 0; n < 4; ++n) {
        const size_t col = colBase + wc * 64 + n * 16 + ocol;
        const float bv = (EPI == 0) ? bias[col] : 0.f;
        #pragma unroll
        for (int m = 0; m < 4; ++m) {
            const size_t rbase = rowBase + wr * 64 + m * 16 + orow;
            #pragma unroll
            for (int j = 0; j < 4; ++j) {
                const float v = acc[m][n][j];
                const size_t off = (size_t)blockIdx.z * cB + (rbase + j) * (size_t)N + col;
                if (EPI == 0)      ((short*)Cv)[off] = f2bf(v + bv);
                else if (EPI == 1) ((float*)Cv)[off] = v * scale;
                else               ((float*)Cv)[off] = v;
            }
        }
    }
}

// ---------- masked row softmax over D=4096; writes f32 output + bf16 copy ----------
__global__ void softmax_rows(const float* __restrict__ scores, const int* __restrict__ mask,
                             float* __restrict__ attnF, short* __restrict__ attnB) {
    const int row = blockIdx.x;          // b*Q + q
    const int b   = row >> 9;            // / QLEN
    const int tid = threadIdx.x;
    const int lane = tid & 63;
    const int wv = tid >> 6;
    const float4* S  = (const float4*)(scores + (size_t)row * DLEN);
    const int4*   Mk = (const int4*)(mask + (size_t)b * DLEN);
    __shared__ float red[8];

    float v[16];
    float mx = -INFINITY;
    #pragma unroll
    for (int i = 0; i < 4; ++i) {
        float4 s = S[i * 256 + tid];
        int4   m = Mk[i * 256 + tid];
        v[i * 4 + 0] = m.x ? s.x : -INFINITY;
        v[i * 4 + 1] = m.y ? s.y : -INFINITY;
        v[i * 4 + 2] = m.z ? s.z : -INFINITY;
        v[i * 4 + 3] = m.w ? s.w : -INFINITY;
        #pragma unroll
        for (int c = 0; c < 4; ++c) mx = fmaxf(mx, v[i * 4 + c]);
    }
    #pragma unroll
    for (int o = 32; o > 0; o >>= 1) mx = fmaxf(mx, __shfl_xor(mx, o));
    if (lane == 0) red[wv] = mx;
    __syncthreads();
    mx = fmaxf(fmaxf(red[0], red[1]), fmaxf(red[2], red[3]));

    float sum = 0.f;
    #pragma unroll
    for (int i = 0; i < 16; ++i) {
        float e = __expf(v[i] - mx);   // masked: exp(-inf) = 0
        v[i] = e;
        sum += e;
    }
    #pragma unroll
    for (int o = 32; o > 0; o >>= 1) sum += __shfl_xor(sum, o);
    __syncthreads();
    if (lane == 0) red[4 + wv] = sum;
    __syncthreads();
    sum = red[4] + red[5] + red[6] + red[7];
    const float inv = 1.0f / sum;

    float4* OF = (float4*)(attnF + (size_t)row * DLEN);
    s16x4*  OB = (s16x4*)(attnB + (size_t)row * DLEN);
    #pragma unroll
    for (int i = 0; i < 4; ++i) {
        float4 w;
        w.x = v[i * 4 + 0] * inv;
        w.y = v[i * 4 + 1] * inv;
        w.z = v[i * 4 + 2] * inv;
        w.w = v[i * 4 + 3] * inv;
        OF[i * 256 + tid] = w;
        s16x4 o = { f2bf(w.x), f2bf(w.y), f2bf(w.z), f2bf(w.w) };
        OB[i * 256 + tid] = o;
    }
}

// ---------- launch ----------
extern "C" void kernel_launch(void* const* d_in, const int* in_sizes, int n_in,
                              void* d_out, int out_size, void* d_ws, size_t ws_size,
                              hipStream_t stream) {
    const float* qe   = (const float*)d_in[0];   // [8,512,1024]
    const float* docs = (const float*)d_in[1];   // [8,4096,1024]
    const int*   mask = (const int*)d_in[2];     // [8,4096]
    const float* pw   = (const float*)d_in[3];   // [1024,1024]
    const float* pb   = (const float*)d_in[4];   // [1024]

    float* outRet  = (float*)d_out;                          // [8,512,1024]
    float* outAttn = outRet + (size_t)BATCH * QLEN * HDIM;   // [8,512,4096]

    // workspace layout (bytes)
    char* ws = (char*)d_ws;
    short* qeB   = (short*)(ws + 0);            //  8 MiB: [4096][1024] bf16
    short* wt    = (short*)(ws + 8388608);      //  2 MiB: Wt [k][h] bf16
    short* qpB   = (short*)(ws + 10485760);     //  8 MiB: projected q bf16
    short* docsB = (short*)(ws + 18874368);     // 64 MiB: docs bf16 [b][d][h]
    short* docsT = (short*)(ws + 85983232);     // 64 MiB: docsT bf16 [b][h][d]
    float* scor  = (float*)(ws + 153092096);    // 64 MiB: scores f32 [b][q][d]
    short* attnB = (short*)(ws + 220200960);    // 32 MiB: attn bf16 [b][q][d]

    // prep
    cvt_f32_bf16<<<dim3(1024), dim3(256), 0, stream>>>(qe, qeB, (BATCH * QLEN * HDIM) / 4);
    transpose_w<<<dim3(32, 32), dim3(32, 8), 0, stream>>>(pw, wt);
    prep_docs<<<dim3(32, 128, 8), dim3(32, 8), 0, stream>>>(docs, docsB, docsT);

    // GEMM1: q = qe @ W + b   (M=4096, N=1024, K=1024) -> bf16
    gemm_bt<0><<<dim3(HDIM / BN, (BATCH * QLEN) / BM, 1), dim3(256), 0, stream>>>(
        qeB, wt, (void*)qpB, pb, 1.f, BATCH * QLEN, HDIM, HDIM, 0LL, 0LL, 0LL);

    // GEMM2: scores = q @ docs^T * scale  (per batch M=512, N=4096, K=1024) -> f32
    gemm_bt<1><<<dim3(DLEN / BN, QLEN / BM, BATCH), dim3(256), 0, stream>>>(
        qpB, docsB, (void*)scor, nullptr, 0.03125f, QLEN, DLEN, HDIM,
        (long long)QLEN * HDIM, (long long)DLEN * HDIM, (long long)QLEN * DLEN);

    // softmax rows (4096 rows of 4096) -> f32 output + bf16 for PV
    softmax_rows<<<dim3(BATCH * QLEN), dim3(256), 0, stream>>>(scor, mask, outAttn, attnB);

    // GEMM3: retrieved = attn @ docs  (per batch M=512, N=1024, K=4096) -> f32
    gemm_bt<2><<<dim3(HDIM / BN, QLEN / BM, BATCH), dim3(256), 0, stream>>>(
        attnB, docsT, (void*)outRet, nullptr, 1.f, QLEN, HDIM, DLEN,
        (long long)QLEN * DLEN, (long long)HDIM * DLEN, (long long)QLEN * HDIM);
}

// Round 2
// 434.154 us; speedup vs baseline: 1.0829x; 1.0829x over previous
//
#include <hip/hip_runtime.h>

// Problem constants (B=8, Q=512, D=4096, H=1024)
#define BATCH 8
#define QLEN 512
#define DLEN 4096
#define HDIM 1024

// ---------- helpers ----------
typedef __attribute__((ext_vector_type(8))) short bf16x8;   // 8 bf16 in 4 VGPRs
typedef __attribute__((ext_vector_type(4))) float f32x4;
typedef __attribute__((ext_vector_type(4))) short s16x4;

__device__ __forceinline__ short f2bf(float f) {
    union { float f; unsigned u; } x; x.f = f;
    unsigned r = x.u + 0x7fffu + ((x.u >> 16) & 1u);   // RNE
    return (short)(r >> 16);
}

__device__ __forceinline__ void gload_lds16(const void* g, void* l) {
    __builtin_amdgcn_global_load_lds(
        (const __attribute__((address_space(1))) unsigned int*)g,
        (__attribute__((address_space(3))) unsigned int*)l,
        16, 0, 0);
}

// ---------- prep kernels ----------
// fp32 -> bf16 elementwise (vectorized float4 -> short4)
__global__ void cvt_f32_bf16(const float* __restrict__ in, short* __restrict__ out, int n4) {
    int i = blockIdx.x * blockDim.x + threadIdx.x;
    int stride = gridDim.x * blockDim.x;
    for (; i < n4; i += stride) {
        float4 x = ((const float4*)in)[i];
        s16x4 o = { f2bf(x.x), f2bf(x.y), f2bf(x.z), f2bf(x.w) };
        ((s16x4*)out)[i] = o;
    }
}

// proj_w [h][k] f32 -> Wt [k][h] bf16  (1024x1024), 32x32 LDS tile transpose
__global__ void transpose_w(const float* __restrict__ W, short* __restrict__ Wt) {
    __shared__ float t[32][33];
    const int hb = blockIdx.y * 32, kb = blockIdx.x * 32;
    #pragma unroll
    for (int i = 0; i < 4; ++i) {
        int h = threadIdx.y + i * 8;
        t[h][threadIdx.x] = W[(size_t)(hb + h) * HDIM + kb + threadIdx.x];
    }
    __syncthreads();
    #pragma unroll
    for (int i = 0; i < 4; ++i) {
        int k = threadIdx.y + i * 8;
        Wt[(size_t)(kb + k) * HDIM + hb + threadIdx.x] = f2bf(t[threadIdx.x][k]);
    }
}

// docs [b][d][h] f32 -> docsB [b][d][h] bf16  AND  docsT [b][h][d] bf16
// 64x64 tile, float4 loads, short4 stores both ways, [64][65] scalar-LDS transpose.
__global__ void prep_docs(const float* __restrict__ docs,
                          short* __restrict__ docsB, short* __restrict__ docsT) {
    __shared__ float t[64][65];
    const int b = blockIdx.z;
    const int h0 = blockIdx.x * 64, d0 = blockIdx.y * 64;
    const int tq = threadIdx.x & 15;   // quad index (4 elems)
    const int tr = threadIdx.x >> 4;   // row group
    const float* src = docs + ((size_t)b * DLEN + d0) * HDIM + h0;
    #pragma unroll
    for (int i = 0; i < 4; ++i) {
        int d = tr + i * 16;
        float4 v = *(const float4*)(src + (size_t)d * HDIM + tq * 4);
        t[d][tq * 4 + 0] = v.x;
        t[d][tq * 4 + 1] = v.y;
        t[d][tq * 4 + 2] = v.z;
        t[d][tq * 4 + 3] = v.w;
        s16x4 o = { f2bf(v.x), f2bf(v.y), f2bf(v.z), f2bf(v.w) };
        *(s16x4*)(docsB + ((size_t)b * DLEN + d0 + d) * HDIM + h0 + tq * 4) = o;
    }
    __syncthreads();
    #pragma unroll
    for (int i = 0; i < 4; ++i) {
        int h = tr + i * 16;              // column of t = output row
        s16x4 o = { f2bf(t[tq * 4 + 0][h]), f2bf(t[tq * 4 + 1][h]),
                    f2bf(t[tq * 4 + 2][h]), f2bf(t[tq * 4 + 3][h]) };
        *(s16x4*)(docsT + ((size_t)b * HDIM + h0 + h) * DLEN + d0 + tq * 4) = o;
    }
}

// ---------- GEMM: D[i][j] = dot(A_i, B_j), A,B bf16 row-major in K ----------
// 128x128 tile, BK=64 (128B rows = 8x16B chunks), XOR chunk-swizzle:
//   physical chunk (r, cc) holds global chunk (r, cc ^ (r&7));
//   global_load_lds keeps LINEAR LDS dest, source address pre-swizzled (rule #21).
// Reads XOR the same way -> each 16-lane group covers all 8 bank-quads (2/bank, free).
// z-decomposition: b = z & 7, split = z >> 3, kOff = split*kOffStep.
// EPI 0: bf16 out + bias   EPI 1: f32 out * scale   EPI 2: f32 out (partials)
#define BM 128
#define BN 128
#define BK 64

template<int EPI>
__global__ void gemm_bt(const short* __restrict__ A, const short* __restrict__ B,
                        void* __restrict__ Cv, const float* __restrict__ bias,
                        float scale, int N, int Kstride, int Kloop, int kOffStep,
                        long long aB, long long bB, long long cB) {
    __shared__ short As[BM * BK];
    __shared__ short Bs[BN * BK];
    const int tid  = threadIdx.x;
    const int lane = tid & 63;
    const int wv   = tid >> 6;
    const int wr   = wv >> 1, wc = wv & 1;
    const size_t rowBase = (size_t)blockIdx.y * BM;
    const size_t colBase = (size_t)blockIdx.x * BN;
    const int z = blockIdx.z;
    const int bb = z & 7;
    const int kOff = (z >> 3) * kOffStep;
    const short* Ag = A + (size_t)bb * aB + kOff;
    const short* Bg = B + (size_t)bb * bB + kOff;

    f32x4 acc[4][4];
    #pragma unroll
    for (int m = 0; m < 4; ++m)
        #pragma unroll
        for (int n = 0; n < 4; ++n)
            acc[m][n] = (f32x4){0.f, 0.f, 0.f, 0.f};

    // staging: 1024 chunks of 16B per tile, 4 per thread; precompute swizzled srcs
    const short* aSrc[4]; const short* bSrc[4]; short* aDst[4]; short* bDst[4];
    #pragma unroll
    for (int i = 0; i < 4; ++i) {
        const int c = tid + 256 * i;
        const int r = c >> 3, cc = c & 7;
        const int gk = (cc ^ (r & 7)) << 3;     // inverse-swizzled global chunk
        aSrc[i] = Ag + (rowBase + r) * (size_t)Kstride + gk;
        bSrc[i] = Bg + (colBase + r) * (size_t)Kstride + gk;
        aDst[i] = As + c * 8;                    // linear LDS dest
        bDst[i] = Bs + c * 8;
    }
    const int lr = lane & 15;
    const int lk = (lane >> 4) << 3;            // 0,8,16,24 shorts

    for (int kt = 0; kt < Kloop; kt += BK) {
        #pragma unroll
        for (int i = 0; i < 4; ++i) gload_lds16(aSrc[i] + kt, aDst[i]);
        #pragma unroll
        for (int i = 0; i < 4; ++i) gload_lds16(bSrc[i] + kt, bDst[i]);
        __syncthreads();

        #pragma unroll
        for (int kk = 0; kk < 2; ++kk) {
            const int chunkL = (kk * 32 + lk) >> 3;   // logical chunk 0..7
            bf16x8 af[4], bfr[4];
            #pragma unroll
            for (int m = 0; m < 4; ++m) {
                const int row = wr * 64 + m * 16 + lr;
                af[m] = *(const bf16x8*)(As + row * BK + ((chunkL ^ (row & 7)) << 3));
            }
            #pragma unroll
            for (int n = 0; n < 4; ++n) {
                const int row = wc * 64 + n * 16 + lr;
                bfr[n] = *(const bf16x8*)(Bs + row * BK + ((chunkL ^ (row & 7)) << 3));
            }
            #pragma unroll
            for (int m = 0; m < 4; ++m)
                #pragma unroll
                for (int n = 0; n < 4; ++n)
                    acc[m][n] = __builtin_amdgcn_mfma_f32_16x16x32_bf16(af[m], bfr[n], acc[m][n], 0, 0, 0);
        }
        __syncthreads();
    }

    // epilogue: C/D layout col=lane&15, row=(lane>>4)*4+reg  [m89/m91-verified]
    const int orow = (lane >> 4) << 2;
    const int ocol = lane & 15;
    #pragma unroll
    for (int n = 0; n < 4; ++n) {
        const size_t col = colBase + wc * 64 + n * 16 + ocol;
        const float bv = (EPI == 0) ? bias[col] : 0.f;
        #pragma unroll
        for (int m = 0; m < 4; ++m) {
            const size_t rbase = rowBase + wr * 64 + m * 16 + orow;
            #pragma unroll
            for (int j = 0; j < 4; ++j) {
                const float v = acc[m][n][j];
                const size_t off = (size_t)z * cB + (rbase + j) * (size_t)N + col;
                if (EPI == 0)      ((short*)Cv)[off] = f2bf(v + bv);
                else if (EPI == 1) ((float*)Cv)[off] = v * scale;
                else               ((float*)Cv)[off] = v;
            }
        }
    }
}

// ---------- split-K reduce: out4[i] = sum_{s<4} p4[i + s*2^20] ----------
__global__ void reduce4(const float* __restrict__ p, float* __restrict__ out, int n4) {
    int i = blockIdx.x * blockDim.x + threadIdx.x;
    const int stride = gridDim.x * blockDim.x;
    const float4* p4 = (const float4*)p;
    float4* o4 = (float4*)out;
    for (; i < n4; i += stride) {
        float4 a = p4[i];
        float4 b = p4[i + 1048576];
        float4 c = p4[i + 2097152];
        float4 d = p4[i + 3145728];
        float4 r;
        r.x = a.x + b.x + c.x + d.x;
        r.y = a.y + b.y + c.y + d.y;
        r.z = a.z + b.z + c.z + d.z;
        r.w = a.w + b.w + c.w + d.w;
        o4[i] = r;
    }
}

// ---------- masked row softmax over D=4096; writes f32 output + bf16 copy ----------
__global__ void softmax_rows(const float* __restrict__ scores, const int* __restrict__ mask,
                             float* __restrict__ attnF, short* __restrict__ attnB) {
    const int row = blockIdx.x;          // b*Q + q
    const int b   = row >> 9;            // / QLEN
    const int tid = threadIdx.x;
    const int lane = tid & 63;
    const int wv = tid >> 6;
    const float4* S  = (const float4*)(scores + (size_t)row * DLEN);
    const int4*   Mk = (const int4*)(mask + (size_t)b * DLEN);
    __shared__ float red[8];

    float v[16];
    float mx = -INFINITY;
    #pragma unroll
    for (int i = 0; i < 4; ++i) {
        float4 s = S[i * 256 + tid];
        int4   m = Mk[i * 256 + tid];
        v[i * 4 + 0] = m.x ? s.x : -INFINITY;
        v[i * 4 + 1] = m.y ? s.y : -INFINITY;
        v[i * 4 + 2] = m.z ? s.z : -INFINITY;
        v[i * 4 + 3] = m.w ? s.w : -INFINITY;
        #pragma unroll
        for (int c = 0; c < 4; ++c) mx = fmaxf(mx, v[i * 4 + c]);
    }
    #pragma unroll
    for (int o = 32; o > 0; o >>= 1) mx = fmaxf(mx, __shfl_xor(mx, o));
    if (lane == 0) red[wv] = mx;
    __syncthreads();
    mx = fmaxf(fmaxf(red[0], red[1]), fmaxf(red[2], red[3]));

    float sum = 0.f;
    #pragma unroll
    for (int i = 0; i < 16; ++i) {
        float e = __expf(v[i] - mx);   // masked: exp(-inf) = 0
        v[i] = e;
        sum += e;
    }
    #pragma unroll
    for (int o = 32; o > 0; o >>= 1) sum += __shfl_xor(sum, o);
    __syncthreads();
    if (lane == 0) red[4 + wv] = sum;
    __syncthreads();
    sum = red[4] + red[5] + red[6] + red[7];
    const float inv = 1.0f / sum;

    float4* OF = (float4*)(attnF + (size_t)row * DLEN);
    s16x4*  OB = (s16x4*)(attnB + (size_t)row * DLEN);
    #pragma unroll
    for (int i = 0; i < 4; ++i) {
        float4 w;
        w.x = v[i * 4 + 0] * inv;
        w.y = v[i * 4 + 1] * inv;
        w.z = v[i * 4 + 2] * inv;
        w.w = v[i * 4 + 3] * inv;
        OF[i * 256 + tid] = w;
        s16x4 o = { f2bf(w.x), f2bf(w.y), f2bf(w.z), f2bf(w.w) };
        OB[i * 256 + tid] = o;
    }
}

// ---------- launch ----------
extern "C" void kernel_launch(void* const* d_in, const int* in_sizes, int n_in,
                              void* d_out, int out_size, void* d_ws, size_t ws_size,
                              hipStream_t stream) {
    const float* qe   = (const float*)d_in[0];   // [8,512,1024]
    const float* docs = (const float*)d_in[1];   // [8,4096,1024]
    const int*   mask = (const int*)d_in[2];     // [8,4096]
    const float* pw   = (const float*)d_in[3];   // [1024,1024]
    const float* pb   = (const float*)d_in[4];   // [1024]

    float* outRet  = (float*)d_out;                          // [8,512,1024]
    float* outAttn = outRet + (size_t)BATCH * QLEN * HDIM;   // [8,512,4096]

    // workspace layout (bytes)
    char* ws = (char*)d_ws;
    short* qeB   = (short*)(ws + 0);            //  8 MiB: [4096][1024] bf16
    short* wt    = (short*)(ws + 8388608);      //  2 MiB: Wt [k][h] bf16
    short* qpB   = (short*)(ws + 10485760);     //  8 MiB: projected q bf16
    short* docsB = (short*)(ws + 18874368);     // 64 MiB: docs bf16 [b][d][h]
    short* docsT = (short*)(ws + 85983232);     // 64 MiB: docsT bf16 [b][h][d]
    float* scor  = (float*)(ws + 153092096);    // 64 MiB: scores f32 / GEMM3 partials
    short* attnB = (short*)(ws + 220200960);    // 32 MiB: attn bf16 [b][q][d]

    // prep
    cvt_f32_bf16<<<dim3(1024), dim3(256), 0, stream>>>(qe, qeB, (BATCH * QLEN * HDIM) / 4);
    transpose_w<<<dim3(32, 32), dim3(32, 8), 0, stream>>>(pw, wt);
    prep_docs<<<dim3(HDIM / 64, DLEN / 64, BATCH), dim3(256), 0, stream>>>(docs, docsB, docsT);

    // GEMM1: q = qe @ W + b   (M=4096, N=1024, K=1024) -> bf16
    gemm_bt<0><<<dim3(HDIM / BN, (BATCH * QLEN) / BM, 1), dim3(256), 0, stream>>>(
        qeB, wt, (void*)qpB, pb, 1.f, HDIM, HDIM, HDIM, 0,
        0LL, 0LL, 0LL);

    // GEMM2: scores = q @ docs^T * scale  (per batch M=512, N=4096, K=1024) -> f32
    gemm_bt<1><<<dim3(DLEN / BN, QLEN / BM, BATCH), dim3(256), 0, stream>>>(
        qpB, docsB, (void*)scor, nullptr, 0.03125f, DLEN, HDIM, HDIM, 0,
        (long long)QLEN * HDIM, (long long)DLEN * HDIM, (long long)QLEN * DLEN);

    // softmax rows (4096 rows of 4096) -> f32 output + bf16 for PV
    softmax_rows<<<dim3(BATCH * QLEN), dim3(256), 0, stream>>>(scor, mask, outAttn, attnB);

    // GEMM3 split-K=4: partial[z=split*8+b] = attn @ docs over K-chunk of 1024
    // partials overwrite scor (64 MiB, exactly 32 * 512*1024 * 4B)
    gemm_bt<2><<<dim3(HDIM / BN, QLEN / BM, BATCH * 4), dim3(256), 0, stream>>>(
        attnB, docsT, (void*)scor, nullptr, 1.f, HDIM, DLEN, DLEN / 4, DLEN / 4,
        (long long)QLEN * DLEN, (long long)HDIM * DLEN, (long long)QLEN * HDIM);

    // reduce partials -> retrieved docs
    reduce4<<<dim3(2048), dim3(256), 0, stream>>>(scor, outRet, (BATCH * QLEN * HDIM) / 4);
}

// Round 3
// 414.389 us; speedup vs baseline: 1.1346x; 1.0477x over previous
//
#include <hip/hip_runtime.h>

// Problem constants (B=8, Q=512, D=4096, H=1024)
#define BATCH 8
#define QLEN 512
#define DLEN 4096
#define HDIM 1024

// ---------- helpers ----------
typedef __attribute__((ext_vector_type(8))) short bf16x8;   // 8 bf16 in 4 VGPRs
typedef __attribute__((ext_vector_type(4))) float f32x4;
typedef __attribute__((ext_vector_type(4))) short s16x4;

__device__ __forceinline__ short f2bf(float f) {
    union { float f; unsigned u; } x; x.f = f;
    unsigned r = x.u + 0x7fffu + ((x.u >> 16) & 1u);   // RNE
    return (short)(r >> 16);
}

__device__ __forceinline__ void gload_lds16(const void* g, void* l) {
    __builtin_amdgcn_global_load_lds(
        (const __attribute__((address_space(1))) unsigned int*)g,
        (__attribute__((address_space(3))) unsigned int*)l,
        16, 0, 0);
}

// ---------- prep kernels ----------
// fp32 -> bf16 elementwise (vectorized float4 -> short4)
__global__ void cvt_f32_bf16(const float* __restrict__ in, short* __restrict__ out, int n4) {
    int i = blockIdx.x * blockDim.x + threadIdx.x;
    int stride = gridDim.x * blockDim.x;
    for (; i < n4; i += stride) {
        float4 x = ((const float4*)in)[i];
        s16x4 o = { f2bf(x.x), f2bf(x.y), f2bf(x.z), f2bf(x.w) };
        ((s16x4*)out)[i] = o;
    }
}

// proj_w [h][k] f32 -> Wt [k][h] bf16  (1024x1024), 32x32 LDS tile transpose
__global__ void transpose_w(const float* __restrict__ W, short* __restrict__ Wt) {
    __shared__ float t[32][33];
    const int hb = blockIdx.y * 32, kb = blockIdx.x * 32;
    #pragma unroll
    for (int i = 0; i < 4; ++i) {
        int h = threadIdx.y + i * 8;
        t[h][threadIdx.x] = W[(size_t)(hb + h) * HDIM + kb + threadIdx.x];
    }
    __syncthreads();
    #pragma unroll
    for (int i = 0; i < 4; ++i) {
        int k = threadIdx.y + i * 8;
        Wt[(size_t)(kb + k) * HDIM + hb + threadIdx.x] = f2bf(t[threadIdx.x][k]);
    }
}

// docsB [b][d][h] bf16 -> docsT [b][h][d] bf16. 64x64 tile via uint LDS [64][65]
// (bank: (65r+c) mod 32 spreads both phases to 2 lanes/bank = free, m136).
__global__ void transpose_docs(const short* __restrict__ docsB, short* __restrict__ docsT) {
    __shared__ unsigned t[64][65];
    const int b = blockIdx.z;
    const int h0 = blockIdx.x * 64, d0 = blockIdx.y * 64;
    const int tq = threadIdx.x & 15;
    const int tr = threadIdx.x >> 4;
    #pragma unroll
    for (int i = 0; i < 4; ++i) {
        int d = tr + i * 16;
        s16x4 v = *(const s16x4*)(docsB + ((size_t)b * DLEN + d0 + d) * HDIM + h0 + tq * 4);
        t[d][tq * 4 + 0] = (unsigned short)v[0];
        t[d][tq * 4 + 1] = (unsigned short)v[1];
        t[d][tq * 4 + 2] = (unsigned short)v[2];
        t[d][tq * 4 + 3] = (unsigned short)v[3];
    }
    __syncthreads();
    #pragma unroll
    for (int i = 0; i < 4; ++i) {
        int h = tr + i * 16;
        s16x4 o = { (short)t[tq * 4 + 0][h], (short)t[tq * 4 + 1][h],
                    (short)t[tq * 4 + 2][h], (short)t[tq * 4 + 3][h] };
        *(s16x4*)(docsT + ((size_t)b * HDIM + h0 + h) * DLEN + d0 + tq * 4) = o;
    }
}

// ---------- GEMM: D[i][j] = dot(A_i, B_j), A,B bf16 row-major in K ----------
// 128x128 tile, BK=64 (128B rows = 8x16B chunks), XOR chunk-swizzle (rule #21:
// linear LDS dest for global_load_lds, source pre-swizzled, reads same XOR).
// 1D grid + T1 XCD chunk swizzle: logical wg = (bid%8)*(nwg/8) + bid/8 (nwg%8==0),
// then decode bx = wg & (2^sx-1), by = (wg>>sx) & (2^(sxy-sx)-1), z = wg>>sxy.
// z-decomposition: b = z & 7, split = z >> 3, kOff = split*kOffStep.
// EPI 0: bf16 out + bias   EPI 1: f32 out * scale   EPI 2: f32 out (partials)
#define BM 128
#define BN 128
#define BK 64

template<int EPI>
__global__ void gemm_bt(const short* __restrict__ A, const short* __restrict__ B,
                        void* __restrict__ Cv, const float* __restrict__ bias,
                        float scale, int N, int Kstride, int Kloop, int kOffStep,
                        int sx, int sxy,
                        long long aB, long long bB, long long cB) {
    __shared__ short As[BM * BK];
    __shared__ short Bs[BN * BK];
    const int tid  = threadIdx.x;
    const int lane = tid & 63;
    const int wv   = tid >> 6;
    const int wr   = wv >> 1, wc = wv & 1;

    // T1 XCD chunk swizzle (bijective since gridDim.x % 8 == 0)
    const int wg = (blockIdx.x & 7) * (gridDim.x >> 3) + (blockIdx.x >> 3);
    const int bx = wg & ((1 << sx) - 1);
    const int by = (wg >> sx) & ((1 << (sxy - sx)) - 1);
    const int z  = wg >> sxy;

    const size_t rowBase = (size_t)by * BM;
    const size_t colBase = (size_t)bx * BN;
    const int bb = z & 7;
    const int kOff = (z >> 3) * kOffStep;
    const short* Ag = A + (size_t)bb * aB + kOff;
    const short* Bg = B + (size_t)bb * bB + kOff;

    f32x4 acc[4][4];
    #pragma unroll
    for (int m = 0; m < 4; ++m)
        #pragma unroll
        for (int n = 0; n < 4; ++n)
            acc[m][n] = (f32x4){0.f, 0.f, 0.f, 0.f};

    // staging: 1024 chunks of 16B per tile, 4 per thread; precompute swizzled srcs
    const short* aSrc[4]; const short* bSrc[4]; short* aDst[4]; short* bDst[4];
    #pragma unroll
    for (int i = 0; i < 4; ++i) {
        const int c = tid + 256 * i;
        const int r = c >> 3, cc = c & 7;
        const int gk = (cc ^ (r & 7)) << 3;     // inverse-swizzled global chunk
        aSrc[i] = Ag + (rowBase + r) * (size_t)Kstride + gk;
        bSrc[i] = Bg + (colBase + r) * (size_t)Kstride + gk;
        aDst[i] = As + c * 8;                    // linear LDS dest
        bDst[i] = Bs + c * 8;
    }
    const int lr = lane & 15;
    const int lk = (lane >> 4) << 3;            // 0,8,16,24 shorts

    for (int kt = 0; kt < Kloop; kt += BK) {
        #pragma unroll
        for (int i = 0; i < 4; ++i) gload_lds16(aSrc[i] + kt, aDst[i]);
        #pragma unroll
        for (int i = 0; i < 4; ++i) gload_lds16(bSrc[i] + kt, bDst[i]);
        __syncthreads();

        #pragma unroll
        for (int kk = 0; kk < 2; ++kk) {
            const int chunkL = (kk * 32 + lk) >> 3;   // logical chunk 0..7
            bf16x8 af[4], bfr[4];
            #pragma unroll
            for (int m = 0; m < 4; ++m) {
                const int row = wr * 64 + m * 16 + lr;
                af[m] = *(const bf16x8*)(As + row * BK + ((chunkL ^ (row & 7)) << 3));
            }
            #pragma unroll
            for (int n = 0; n < 4; ++n) {
                const int row = wc * 64 + n * 16 + lr;
                bfr[n] = *(const bf16x8*)(Bs + row * BK + ((chunkL ^ (row & 7)) << 3));
            }
            #pragma unroll
            for (int m = 0; m < 4; ++m)
                #pragma unroll
                for (int n = 0; n < 4; ++n)
                    acc[m][n] = __builtin_amdgcn_mfma_f32_16x16x32_bf16(af[m], bfr[n], acc[m][n], 0, 0, 0);
        }
        __syncthreads();
    }

    // epilogue: C/D layout col=lane&15, row=(lane>>4)*4+reg  [m89/m91-verified]
    const int orow = (lane >> 4) << 2;
    const int ocol = lane & 15;
    #pragma unroll
    for (int n = 0; n < 4; ++n) {
        const size_t col = colBase + wc * 64 + n * 16 + ocol;
        const float bv = (EPI == 0) ? bias[col] : 0.f;
        #pragma unroll
        for (int m = 0; m < 4; ++m) {
            const size_t rbase = rowBase + wr * 64 + m * 16 + orow;
            #pragma unroll
            for (int j = 0; j < 4; ++j) {
                const float v = acc[m][n][j];
                const size_t off = (size_t)z * cB + (rbase + j) * (size_t)N + col;
                if (EPI == 0)      ((short*)Cv)[off] = f2bf(v + bv);
                else if (EPI == 1) ((float*)Cv)[off] = v * scale;
                else               ((float*)Cv)[off] = v;
            }
        }
    }
}

// ---------- split-K reduce: out4[i] = sum_{s<4} p4[i + s*2^20] ----------
__global__ void reduce4(const float* __restrict__ p, float* __restrict__ out, int n4) {
    int i = blockIdx.x * blockDim.x + threadIdx.x;
    const int stride = gridDim.x * blockDim.x;
    const float4* p4 = (const float4*)p;
    float4* o4 = (float4*)out;
    for (; i < n4; i += stride) {
        float4 a = p4[i];
        float4 b = p4[i + 1048576];
        float4 c = p4[i + 2097152];
        float4 d = p4[i + 3145728];
        float4 r;
        r.x = a.x + b.x + c.x + d.x;
        r.y = a.y + b.y + c.y + d.y;
        r.z = a.z + b.z + c.z + d.z;
        r.w = a.w + b.w + c.w + d.w;
        o4[i] = r;
    }
}

// ---------- masked row softmax over D=4096; writes f32 output + bf16 copy ----------
__global__ void softmax_rows(const float* __restrict__ scores, const int* __restrict__ mask,
                             float* __restrict__ attnF, short* __restrict__ attnB) {
    const int row = blockIdx.x;          // b*Q + q
    const int b   = row >> 9;            // / QLEN
    const int tid = threadIdx.x;
    const int lane = tid & 63;
    const int wv = tid >> 6;
    const float4* S  = (const float4*)(scores + (size_t)row * DLEN);
    const int4*   Mk = (const int4*)(mask + (size_t)b * DLEN);
    __shared__ float red[8];

    float v[16];
    float mx = -INFINITY;
    #pragma unroll
    for (int i = 0; i < 4; ++i) {
        float4 s = S[i * 256 + tid];
        int4   m = Mk[i * 256 + tid];
        v[i * 4 + 0] = m.x ? s.x : -INFINITY;
        v[i * 4 + 1] = m.y ? s.y : -INFINITY;
        v[i * 4 + 2] = m.z ? s.z : -INFINITY;
        v[i * 4 + 3] = m.w ? s.w : -INFINITY;
        #pragma unroll
        for (int c = 0; c < 4; ++c) mx = fmaxf(mx, v[i * 4 + c]);
    }
    #pragma unroll
    for (int o = 32; o > 0; o >>= 1) mx = fmaxf(mx, __shfl_xor(mx, o));
    if (lane == 0) red[wv] = mx;
    __syncthreads();
    mx = fmaxf(fmaxf(red[0], red[1]), fmaxf(red[2], red[3]));

    float sum = 0.f;
    #pragma unroll
    for (int i = 0; i < 16; ++i) {
        float e = __expf(v[i] - mx);   // masked: exp(-inf) = 0
        v[i] = e;
        sum += e;
    }
    #pragma unroll
    for (int o = 32; o > 0; o >>= 1) sum += __shfl_xor(sum, o);
    __syncthreads();
    if (lane == 0) red[4 + wv] = sum;
    __syncthreads();
    sum = red[4] + red[5] + red[6] + red[7];
    const float inv = 1.0f / sum;

    float4* OF = (float4*)(attnF + (size_t)row * DLEN);
    s16x4*  OB = (s16x4*)(attnB + (size_t)row * DLEN);
    #pragma unroll
    for (int i = 0; i < 4; ++i) {
        float4 w;
        w.x = v[i * 4 + 0] * inv;
        w.y = v[i * 4 + 1] * inv;
        w.z = v[i * 4 + 2] * inv;
        w.w = v[i * 4 + 3] * inv;
        OF[i * 256 + tid] = w;
        s16x4 o = { f2bf(w.x), f2bf(w.y), f2bf(w.z), f2bf(w.w) };
        OB[i * 256 + tid] = o;
    }
}

// ---------- launch ----------
extern "C" void kernel_launch(void* const* d_in, const int* in_sizes, int n_in,
                              void* d_out, int out_size, void* d_ws, size_t ws_size,
                              hipStream_t stream) {
    const float* qe   = (const float*)d_in[0];   // [8,512,1024]
    const float* docs = (const float*)d_in[1];   // [8,4096,1024]
    const int*   mask = (const int*)d_in[2];     // [8,4096]
    const float* pw   = (const float*)d_in[3];   // [1024,1024]
    const float* pb   = (const float*)d_in[4];   // [1024]

    float* outRet  = (float*)d_out;                          // [8,512,1024]
    float* outAttn = outRet + (size_t)BATCH * QLEN * HDIM;   // [8,512,4096]

    // workspace layout (bytes)
    char* ws = (char*)d_ws;
    short* qeB   = (short*)(ws + 0);            //  8 MiB: [4096][1024] bf16
    short* wt    = (short*)(ws + 8388608);      //  2 MiB: Wt [k][h] bf16
    short* qpB   = (short*)(ws + 10485760);     //  8 MiB: projected q bf16
    short* docsB = (short*)(ws + 18874368);     // 64 MiB: docs bf16 [b][d][h]
    short* docsT = (short*)(ws + 85983232);     // 64 MiB: docsT bf16 [b][h][d]
    float* scor  = (float*)(ws + 153092096);    // 64 MiB: scores f32 / GEMM3 partials
    short* attnB = (short*)(ws + 220200960);    // 32 MiB: attn bf16 [b][q][d]

    // prep: streaming cvt passes + bf16 transpose (reads L2/L3-hot docsB)
    cvt_f32_bf16<<<dim3(1024), dim3(256), 0, stream>>>(qe, qeB, (BATCH * QLEN * HDIM) / 4);
    cvt_f32_bf16<<<dim3(2048), dim3(256), 0, stream>>>(docs, docsB, (BATCH * DLEN * HDIM) / 4);
    transpose_w<<<dim3(32, 32), dim3(32, 8), 0, stream>>>(pw, wt);
    transpose_docs<<<dim3(HDIM / 64, DLEN / 64, BATCH), dim3(256), 0, stream>>>(docsB, docsT);

    // GEMM1: q = qe @ W + b   (M=4096, N=1024, K=1024) -> bf16
    // grid 256 = 8(x) * 32(y): sx=3, sxy=8 (z=0)
    gemm_bt<0><<<dim3(256), dim3(256), 0, stream>>>(
        qeB, wt, (void*)qpB, pb, 1.f, HDIM, HDIM, HDIM, 0, 3, 8,
        0LL, 0LL, 0LL);

    // GEMM2: scores = q @ docs^T * scale  (per batch M=512, N=4096, K=1024) -> f32
    // grid 1024 = 32(x) * 4(y) * 8(z): sx=5, sxy=7
    gemm_bt<1><<<dim3(1024), dim3(256), 0, stream>>>(
        qpB, docsB, (void*)scor, nullptr, 0.03125f, DLEN, HDIM, HDIM, 0, 5, 7,
        (long long)QLEN * HDIM, (long long)DLEN * HDIM, (long long)QLEN * DLEN);

    // softmax rows (4096 rows of 4096) -> f32 output + bf16 for PV
    softmax_rows<<<dim3(BATCH * QLEN), dim3(256), 0, stream>>>(scor, mask, outAttn, attnB);

    // GEMM3 split-K=4: partial[z=split*8+b] = attn @ docs over K-chunk of 1024
    // grid 1024 = 8(x) * 4(y) * 32(z): sx=3, sxy=5; partials overwrite scor
    gemm_bt<2><<<dim3(1024), dim3(256), 0, stream>>>(
        attnB, docsT, (void*)scor, nullptr, 1.f, HDIM, DLEN, DLEN / 4, DLEN / 4, 3, 5,
        (long long)QLEN * DLEN, (long long)HDIM * DLEN, (long long)QLEN * HDIM);

    // reduce partials -> retrieved docs
    reduce4<<<dim3(2048), dim3(256), 0, stream>>>(scor, outRet, (BATCH * QLEN * HDIM) / 4);
}